// Round 12
// baseline (52.047 us; speedup 1.0000x reference)
//
#include <hip/hip_runtime.h>
#include <math.h>

// Problem constants (from setup_inputs: batch=1024, dim_z=32, n_samples=32, agg_size=256)
#define B    1024
#define D    32
#define NS   32
#define AGG  256
#define NC   (B / AGG)      // 4 chunks
#define M    (AGG * NS)     // 8192 samples per chunk
#define NJB  8              // j-blocks per (c,k)  (eval)
#define JB   (M / NJB)      // 1024 samples per block
#define TJ   (JB / 256)     // 4 samples per thread
#define NBLK (NC * D * NJB) // 1024 eval blocks -> 4 blocks/CU -> 4 waves/SIMD

// Table geometry: L(z)=log2(sum_i 2^arg_i) on z in [-32,32], h=1/16, 1024 nodes/(c,k).
#define TN     1024
#define ZMIN   (-32.0f)
#define INVH   16.0f
#define HH     0.0625f
#define ZCLAMP 31.9f
#define ZOOB   31.0f

// ws layout: [0] uint counter | @256 float partial[1024] | @8192 float4 params (512KB)
//            | @532480 float2 table[128*1024] (1MB)   -> NEED = 1581056 bytes
#define WS_PARTIAL 256
#define WS_PARAMS  8192
#define WS_TABLE   532480
#define WS_NEED    1581056

// params[(c*D+k)*AGG + i] = {A, B, C, sd}:  arg(z) = A z^2 + B z + C
//   = -0.5*log2e*((z-mu)^2*exp(-lv) + lv),  sd = exp(0.5*lv), mu = -0.5*B/A
__global__ __launch_bounds__(256) void ksetup(const float* __restrict__ mean,
                                              const float* __restrict__ logvar,
                                              float4* __restrict__ params,
                                              unsigned* __restrict__ counter)
{
    constexpr float LOG2E = 1.4426950408889634f;
    const int tid = blockIdx.x * 256 + threadIdx.x;   // over B*D = 32768, k fastest
    if (tid == 0) counter[0] = 0u;                    // reset last-block counter
    const int row = tid >> 5;
    const int k   = tid & (D - 1);
    const int c   = row >> 8;
    const int i   = row & (AGG - 1);
    const float mu = mean[tid];
    const float lv = logvar[tid];
    const float ev = __builtin_amdgcn_exp2f(-lv * LOG2E);      // exp(-lv); lv~N(0,1): safe
    params[((c * D + k) << 8) | i] =
        make_float4(-0.5f * LOG2E * ev,
                    LOG2E * mu * ev,
                    -0.5f * LOG2E * fmaf(mu * mu, ev, lv),
                    __builtin_amdgcn_exp2f(0.5f * LOG2E * lv));
}

// Build L and h*L' per node. 2048 blocks = 128 ck x 16 node-segments of 64.
// Each of the block's 4 waves sums a 64-comp quarter (wave-uniform scalar loads);
// LDS combine (fixed order -> deterministic), 64 threads finish log/rcp/store.
__global__ __launch_bounds__(256) void ktable(const float4* __restrict__ params,
                                              float2* __restrict__ table)
{
    const int bid  = blockIdx.x;
    const int ck   = bid >> 4;
    const int g0   = (bid & 15) << 6;                // node base (64 nodes/block)
    const int t    = threadIdx.x;
    const int lane = t & 63;
    const int qrt  = t >> 6;                         // comp quarter, wave-uniform
    const float4* __restrict__ pk = params + (ck << 8) + (qrt << 6);
    const float z = fmaf((float)(g0 + lane), HH, ZMIN);
    float acc = 0.f, dacc = 0.f;
#pragma unroll 8
    for (int i = 0; i < 64; ++i) {
        const float4 p  = pk[i];
        const float ap  = fmaf(p.x, z, p.y);          // A z + B
        const float w   = __builtin_amdgcn_exp2f(fmaf(ap, z, p.z));
        acc += w;
        dacc = fmaf(w, fmaf(2.0f, ap, -p.y), dacc);   // arg' = 2Az+B = 2*ap - B
    }
    __shared__ float2 part[256];
    part[t] = make_float2(acc, dacc);
    __syncthreads();
    if (t < 64) {
        const float2 p0 = part[t];
        const float2 p1 = part[t + 64];
        const float2 p2 = part[t + 128];
        const float2 p3 = part[t + 192];
        const float a  = (p0.x + p1.x) + (p2.x + p3.x);
        const float d  = (p0.y + p1.y) + (p2.y + p3.y);
        const float ag = fmaxf(a, 1e-30f);            // unused far nodes: no NaN/inf
        table[(ck << 10) | (g0 + t)] =
            make_float2(__builtin_amdgcn_logf(ag),
                        d * __builtin_amdgcn_rcpf(ag) * HH);
    }
}

// Exact 256-exp fallback for |z| > ZOOB (expected ~never; masked lanes only).
static __device__ __noinline__ float exact_log2q(const float4* __restrict__ pk, float z)
{
    float acc = 0.f;
    for (int i = 0; i < AGG; ++i) {
        const float4 p = pk[i];
        acc += __builtin_amdgcn_exp2f(fmaf(fmaf(p.x, z, p.y), z, p.z));
    }
    return __builtin_amdgcn_logf(fmaxf(acc, 1e-30f));
}

__global__ __launch_bounds__(256) void keval(const float* __restrict__ eps,
                                             const float4* __restrict__ params,
                                             const float2* __restrict__ table,
                                             float* __restrict__ partial,
                                             unsigned* __restrict__ counter,
                                             float* __restrict__ out)
{
    constexpr float LN2 = 0.6931471805599453f;
    const int bid = blockIdx.x;
    const int ck  = bid >> 3;                 // c*D + k
    const int q   = bid & 7;
    const int c   = ck >> 5;
    const int k   = ck & (D - 1);
    const int j0  = q * JB;
    const int t   = threadIdx.x;
    const float4* __restrict__ pk = params + (ck << 8);

    // Issue scattered eps gathers first (latency hides under table staging).
    float evv[TJ];
#pragma unroll
    for (int u = 0; u < TJ; ++u)
        evv[u] = eps[(size_t)(c * M + j0 + t + 256 * u) * D + k];

    // Stage this ck's table: 1024 float2 = 8KB, coalesced.
    __shared__ float2 tab[TN];
    const float2* __restrict__ gt = table + (ck << 10);
    tab[t]       = gt[t];
    tab[t + 256] = gt[t + 256];
    tab[t + 512] = gt[t + 512];
    tab[t + 768] = gt[t + 768];
    __syncthreads();

    float r = 0.f;
#pragma unroll
    for (int u = 0; u < TJ; ++u) {
        const int j    = j0 + t + 256 * u;
        const float4 p = pk[j >> 5];                   // own component
        const float mu = -0.5f * p.y * __builtin_amdgcn_rcpf(p.x);
        const float z  = fmaf(evv[u], p.w, mu);

        // cubic Hermite on the staged table
        const float zc = fminf(fmaxf(z, -ZCLAMP), ZCLAMP);
        const float x  = fmaf(zc, INVH, 512.0f);       // (zc - ZMIN)*INVH
        const float fg = floorf(x);
        const float f  = x - fg;
        const int  ig  = (int)fg;                      // in [1,1022]
        const float2 n0 = tab[ig];
        const float2 n1 = tab[ig + 1];
        const float dl  = n1.x - n0.x;
        const float c2  = 3.0f * dl - 2.0f * n0.y - n1.y;
        const float c3  = n0.y + n1.y - 2.0f * dl;
        float L = fmaf(f, fmaf(f, fmaf(f, c3, c2), n0.y), n0.x);
        if (fabsf(z) > ZOOB) L = exact_log2q(pk, z);   // ~never taken
        r += fmaf(LN2, L, 0.5f * z * z);
    }

    // deterministic block reduction
    for (int off = 32; off > 0; off >>= 1) r += __shfl_down(r, off, 64);
    __shared__ float wsum[4];
    if ((t & 63) == 0) wsum[t >> 6] = r;
    __syncthreads();

    // last-block final reduction (deterministic fixed-order sum)
    __shared__ int isLast;
    if (t == 0) {
        partial[bid] = (wsum[0] + wsum[1]) + (wsum[2] + wsum[3]);
        __threadfence();
        const unsigned old = atomicAdd(counter, 1u);
        isLast = (old == (unsigned)(NBLK - 1));
    }
    __syncthreads();
    if (isLast) {
        __threadfence();
        double s = 0.0;
#pragma unroll
        for (int i = 0; i < NBLK / 256; ++i) s += (double)partial[i * 256 + t];
        __shared__ double sd[256];
        sd[t] = s;
        __syncthreads();
        for (int off = 128; off > 0; off >>= 1) {
            if (t < off) sd[t] += sd[t + off];
            __syncthreads();
        }
        if (t == 0)
            out[0] = (float)(sd[0] * (1.0 / (double)(NC * M))
                             - (double)D * 5.545177444479562);   // - D*ln(256)
    }
}

// Fallback (ws too small for the table): direct-exp path (r8 structure, TJ=4).
__global__ __launch_bounds__(256) void kmain(const float* __restrict__ eps,
                                             const float4* __restrict__ params,
                                             float* __restrict__ partial,
                                             unsigned* __restrict__ counter,
                                             float* __restrict__ out)
{
    constexpr float LN2 = 0.6931471805599453f;
    const int bid = blockIdx.x;
    const int ck  = bid >> 3;
    const int q   = bid & 7;
    const int c   = ck >> 5;
    const int k   = ck & (D - 1);
    const int j0  = q * JB;
    const int t   = threadIdx.x;
    const float4* __restrict__ pk = params + (ck << 8);

    float evv[TJ];
#pragma unroll
    for (int u = 0; u < TJ; ++u)
        evv[u] = eps[(size_t)(c * M + j0 + t + 256 * u) * D + k];

    float zv[TJ], acc[TJ];
#pragma unroll
    for (int u = 0; u < TJ; ++u) {
        const float4 p = pk[(t + 256 * u) >> 5];
        const float mu = -0.5f * p.y * __builtin_amdgcn_rcpf(p.x);
        zv[u]  = fmaf(evv[u], p.w, mu);
        acc[u] = 0.f;
    }
#pragma unroll 4
    for (int i = 0; i < AGG; ++i) {
        const float4 p = pk[i];
#pragma unroll
        for (int u = 0; u < TJ; ++u)
            acc[u] += __builtin_amdgcn_exp2f(fmaf(fmaf(p.x, zv[u], p.y), zv[u], p.z));
    }
    float r = 0.f;
#pragma unroll
    for (int u = 0; u < TJ; ++u)
        r += LN2 * __builtin_amdgcn_logf(acc[u]) + 0.5f * zv[u] * zv[u];

    for (int off = 32; off > 0; off >>= 1) r += __shfl_down(r, off, 64);
    __shared__ float wsum[4];
    if ((t & 63) == 0) wsum[t >> 6] = r;
    __syncthreads();
    __shared__ int isLast;
    if (t == 0) {
        partial[bid] = (wsum[0] + wsum[1]) + (wsum[2] + wsum[3]);
        __threadfence();
        const unsigned old = atomicAdd(counter, 1u);
        isLast = (old == (unsigned)(NBLK - 1));
    }
    __syncthreads();
    if (isLast) {
        __threadfence();
        double s = 0.0;
#pragma unroll
        for (int i = 0; i < NBLK / 256; ++i) s += (double)partial[i * 256 + t];
        __shared__ double sd[256];
        sd[t] = s;
        __syncthreads();
        for (int off = 128; off > 0; off >>= 1) {
            if (t < off) sd[t] += sd[t + off];
            __syncthreads();
        }
        if (t == 0)
            out[0] = (float)(sd[0] * (1.0 / (double)(NC * M))
                             - (double)D * 5.545177444479562);
    }
}

extern "C" void kernel_launch(void* const* d_in, const int* in_sizes, int n_in,
                              void* d_out, int out_size, void* d_ws, size_t ws_size,
                              hipStream_t stream)
{
    const float* mean   = (const float*)d_in[0];
    const float* logvar = (const float*)d_in[1];
    const float* eps    = (const float*)d_in[2];
    float* out = (float*)d_out;

    unsigned* counter = (unsigned*)d_ws;
    float*    partial = (float*)((char*)d_ws + WS_PARTIAL);
    float4*   params  = (float4*)((char*)d_ws + WS_PARAMS);
    float2*   table   = (float2*)((char*)d_ws + WS_TABLE);

    ksetup<<<(B * D) / 256, 256, 0, stream>>>(mean, logvar, params, counter);
    if (ws_size >= (size_t)WS_NEED) {
        ktable<<<NC * D * 16, 256, 0, stream>>>(params, table);
        keval<<<NBLK, 256, 0, stream>>>(eps, params, table, partial, counter, out);
    } else {
        kmain<<<NBLK, 256, 0, stream>>>(eps, params, partial, counter, out);
    }
}

// Round 13
// 42.470 us; speedup vs baseline: 1.2255x; 1.2255x over previous
//
#include <hip/hip_runtime.h>
#include <math.h>

// Problem constants (from setup_inputs: batch=1024, dim_z=32, n_samples=32, agg_size=256)
#define B    1024
#define D    32
#define NS   32
#define AGG  256
#define NC   (B / AGG)      // 4 chunks
#define M    (AGG * NS)     // 8192 samples per chunk
#define NJB  4              // j-blocks per (c,k)  (eval)
#define JB   (M / NJB)      // 2048 samples per block
#define TJ   (JB / 256)     // 8 samples per thread
#define NBLK (NC * D * NJB) // 512 eval blocks

// Table geometry: L(z)=log2(sum_i 2^arg_i) on z in [-32,32], h=1/16, 1024 nodes/(c,k).
#define TN     1024
#define ZMIN   (-32.0f)
#define INVH   16.0f
#define HH     0.0625f
#define ZCLAMP 31.9f
#define ZOOB   31.0f

// ws layout: [0] uint counter | @256 float partial[512] | @8192 float4 params (512KB)
//            | @532480 float2 table[128*1024] (1MB) | @1581056 float epsT[4MB]
#define WS_PARTIAL 256
#define WS_PARAMS  8192
#define WS_TABLE   532480
#define WS_EPST    1581056
#define WS_NEED    5775360

// params[(c*D+k)*AGG + i] = {A, B, C, sd}:  arg(z) = A z^2 + B z + C
//   = -0.5*log2e*((z-mu)^2*exp(-lv) + lv),  sd = exp(0.5*lv), mu = -0.5*B/A
__global__ __launch_bounds__(256) void ksetup(const float* __restrict__ mean,
                                              const float* __restrict__ logvar,
                                              float4* __restrict__ params,
                                              unsigned* __restrict__ counter)
{
    constexpr float LOG2E = 1.4426950408889634f;
    const int tid = blockIdx.x * 256 + threadIdx.x;   // over B*D = 32768, k fastest
    if (tid == 0) counter[0] = 0u;                    // reset last-block counter
    const int row = tid >> 5;
    const int k   = tid & (D - 1);
    const int c   = row >> 8;
    const int i   = row & (AGG - 1);
    const float mu = mean[tid];
    const float lv = logvar[tid];
    const float ev = __builtin_amdgcn_exp2f(-lv * LOG2E);      // exp(-lv); lv~N(0,1): safe
    params[((c * D + k) << 8) | i] =
        make_float4(-0.5f * LOG2E * ev,
                    LOG2E * mu * ev,
                    -0.5f * LOG2E * fmaf(mu * mu, ev, lv),
                    __builtin_amdgcn_exp2f(0.5f * LOG2E * lv));
}

// Transpose eps[c][j][k] -> epsT[(c*D+k)][j] via 32x33 LDS tile; both sides coalesced.
// The 128B-lane-stride gather this removes is the hypothesized ~30us floor of r1-r12.
__global__ __launch_bounds__(256) void ktrans(const float* __restrict__ eps,
                                              float* __restrict__ epsT)
{
    const int bid = blockIdx.x;            // 4 * 256 blocks
    const int c   = bid >> 8;
    const int j0t = (bid & 255) << 5;      // 32-sample tile
    const int t   = threadIdx.x;
    const int x   = t & 31;
    const int y0  = t >> 5;                // 8 rows per pass
    __shared__ float tile[32][33];
#pragma unroll
    for (int p = 0; p < 4; ++p) {
        const int r = (p << 3) + y0;
        tile[r][x] = eps[((size_t)c * M + j0t + r) * D + x];   // contiguous 256B/wave
    }
    __syncthreads();
#pragma unroll
    for (int p = 0; p < 4; ++p) {
        const int kk = (p << 3) + y0;
        epsT[(((size_t)c * D + kk) << 13) + j0t + x] = tile[x][kk];  // contiguous 128B/32-lane
    }
}

// Build L and h*L' per node. 512 blocks = 128 ck x 4 node-segments (r11 config:
// 2 blocks/CU -> 8KB K$ footprint, no thrash).
__global__ __launch_bounds__(256) void ktable(const float4* __restrict__ params,
                                              float2* __restrict__ table)
{
    const int bid = blockIdx.x;
    const int ck  = bid >> 2;
    const int g   = ((bid & 3) << 8) | threadIdx.x;   // node 0..1023
    const float4* __restrict__ pk = params + (ck << 8);
    const float z = fmaf((float)g, HH, ZMIN);
    float acc = 0.f, dacc = 0.f;
#pragma unroll 8
    for (int i = 0; i < AGG; ++i) {
        const float4 p  = pk[i];
        const float ap  = fmaf(p.x, z, p.y);          // A z + B
        const float w   = __builtin_amdgcn_exp2f(fmaf(ap, z, p.z));
        acc += w;
        dacc = fmaf(w, fmaf(2.0f, ap, -p.y), dacc);   // arg' = 2Az+B = 2*ap - B
    }
    const float accg = fmaxf(acc, 1e-30f);            // unused far nodes: no NaN/inf
    table[(ck << 10) | g] =
        make_float2(__builtin_amdgcn_logf(accg),
                    dacc * __builtin_amdgcn_rcpf(accg) * HH);
}

// Exact 256-exp fallback for |z| > ZOOB (expected ~never; masked lanes only).
static __device__ __noinline__ float exact_log2q(const float4* __restrict__ pk, float z)
{
    float acc = 0.f;
    for (int i = 0; i < AGG; ++i) {
        const float4 p = pk[i];
        acc += __builtin_amdgcn_exp2f(fmaf(fmaf(p.x, z, p.y), z, p.z));
    }
    return __builtin_amdgcn_logf(fmaxf(acc, 1e-30f));
}

__global__ __launch_bounds__(256) void keval(const float* __restrict__ epsT,
                                             const float4* __restrict__ params,
                                             const float2* __restrict__ table,
                                             float* __restrict__ partial,
                                             unsigned* __restrict__ counter,
                                             float* __restrict__ out)
{
    constexpr float LN2 = 0.6931471805599453f;
    const int bid = blockIdx.x;
    const int ck  = bid >> 2;                 // c*D + k
    const int q   = bid & 3;
    const int j0  = q * JB;
    const int t   = threadIdx.x;
    const float4* __restrict__ pk = params + (ck << 8);

    // Coalesced epsT reads: thread t owns samples j = j0 + 8t + u (u=0..7).
    const float* __restrict__ et = epsT + ((size_t)ck << 13) + j0 + (t << 3);
    const float4 e0 = *(const float4*)(et);
    const float4 e1 = *(const float4*)(et + 4);
    const float e[TJ] = {e0.x, e0.y, e0.z, e0.w, e1.x, e1.y, e1.z, e1.w};

    // All 8 samples share one component row: comp = (j0>>5) + (t>>2).
    const float4 pown = pk[(j0 >> 5) + (t >> 2)];
    const float mu = -0.5f * pown.y * __builtin_amdgcn_rcpf(pown.x);
    const float sd = pown.w;

    // Stage this ck's table: 1024 float2 = 8KB, coalesced.
    __shared__ float2 tab[TN];
    const float2* __restrict__ gt = table + (ck << 10);
    tab[t]       = gt[t];
    tab[t + 256] = gt[t + 256];
    tab[t + 512] = gt[t + 512];
    tab[t + 768] = gt[t + 768];
    __syncthreads();

    float r = 0.f;
#pragma unroll
    for (int u = 0; u < TJ; ++u) {
        const float z  = fmaf(e[u], sd, mu);
        // cubic Hermite on the staged table
        const float zc = fminf(fmaxf(z, -ZCLAMP), ZCLAMP);
        const float x  = fmaf(zc, INVH, 512.0f);       // (zc - ZMIN)*INVH
        const float fg = floorf(x);
        const float f  = x - fg;
        const int  ig  = (int)fg;                      // in [1,1022]
        const float2 n0 = tab[ig];
        const float2 n1 = tab[ig + 1];
        const float dl  = n1.x - n0.x;
        const float c2  = 3.0f * dl - 2.0f * n0.y - n1.y;
        const float c3  = n0.y + n1.y - 2.0f * dl;
        float L = fmaf(f, fmaf(f, fmaf(f, c3, c2), n0.y), n0.x);
        if (fabsf(z) > ZOOB) L = exact_log2q(pk, z);   // ~never taken
        r += fmaf(LN2, L, 0.5f * z * z);
    }

    // deterministic block reduction
    for (int off = 32; off > 0; off >>= 1) r += __shfl_down(r, off, 64);
    __shared__ float wsum[4];
    if ((t & 63) == 0) wsum[t >> 6] = r;
    __syncthreads();

    // last-block final reduction (deterministic fixed-order sum)
    __shared__ int isLast;
    if (t == 0) {
        partial[bid] = (wsum[0] + wsum[1]) + (wsum[2] + wsum[3]);
        __threadfence();
        const unsigned old = atomicAdd(counter, 1u);
        isLast = (old == (unsigned)(NBLK - 1));
    }
    __syncthreads();
    if (isLast) {
        __threadfence();
        double s = 0.0;
#pragma unroll
        for (int i = 0; i < NBLK / 256; ++i) s += (double)partial[i * 256 + t];
        __shared__ double sd2[256];
        sd2[t] = s;
        __syncthreads();
        for (int off = 128; off > 0; off >>= 1) {
            if (t < off) sd2[t] += sd2[t + off];
            __syncthreads();
        }
        if (t == 0)
            out[0] = (float)(sd2[0] * (1.0 / (double)(NC * M))
                             - (double)D * 5.545177444479562);   // - D*ln(256)
    }
}

// Fallback (ws too small for table+epsT): direct-exp r8 path with original gather.
__global__ __launch_bounds__(256) void kmain(const float* __restrict__ eps,
                                             const float4* __restrict__ params,
                                             float* __restrict__ partial,
                                             unsigned* __restrict__ counter,
                                             float* __restrict__ out)
{
    constexpr float LN2 = 0.6931471805599453f;
    const int bid = blockIdx.x;
    const int ck  = bid >> 2;
    const int q   = bid & 3;
    const int c   = ck >> 5;
    const int k   = ck & (D - 1);
    const int j0  = q * JB;
    const int t   = threadIdx.x;
    const float4* __restrict__ pk = params + (ck << 8);

    float evv[TJ];
#pragma unroll
    for (int u = 0; u < TJ; ++u)
        evv[u] = eps[(size_t)(c * M + j0 + t + 256 * u) * D + k];

    float zv[TJ], acc[TJ];
#pragma unroll
    for (int u = 0; u < TJ; ++u) {
        const float4 p = pk[(t + 256 * u) >> 5];
        const float mu = -0.5f * p.y * __builtin_amdgcn_rcpf(p.x);
        zv[u]  = fmaf(evv[u], p.w, mu);
        acc[u] = 0.f;
    }
#pragma unroll 4
    for (int i = 0; i < AGG; ++i) {
        const float4 p = pk[i];
#pragma unroll
        for (int u = 0; u < TJ; ++u)
            acc[u] += __builtin_amdgcn_exp2f(fmaf(fmaf(p.x, zv[u], p.y), zv[u], p.z));
    }
    float r = 0.f;
#pragma unroll
    for (int u = 0; u < TJ; ++u)
        r += LN2 * __builtin_amdgcn_logf(acc[u]) + 0.5f * zv[u] * zv[u];

    for (int off = 32; off > 0; off >>= 1) r += __shfl_down(r, off, 64);
    __shared__ float wsum[4];
    if ((t & 63) == 0) wsum[t >> 6] = r;
    __syncthreads();
    __shared__ int isLast;
    if (t == 0) {
        partial[bid] = (wsum[0] + wsum[1]) + (wsum[2] + wsum[3]);
        __threadfence();
        const unsigned old = atomicAdd(counter, 1u);
        isLast = (old == (unsigned)(NBLK - 1));
    }
    __syncthreads();
    if (isLast) {
        __threadfence();
        double s = 0.0;
#pragma unroll
        for (int i = 0; i < NBLK / 256; ++i) s += (double)partial[i * 256 + t];
        __shared__ double sd2[256];
        sd2[t] = s;
        __syncthreads();
        for (int off = 128; off > 0; off >>= 1) {
            if (t < off) sd2[t] += sd2[t + off];
            __syncthreads();
        }
        if (t == 0)
            out[0] = (float)(sd2[0] * (1.0 / (double)(NC * M))
                             - (double)D * 5.545177444479562);
    }
}

extern "C" void kernel_launch(void* const* d_in, const int* in_sizes, int n_in,
                              void* d_out, int out_size, void* d_ws, size_t ws_size,
                              hipStream_t stream)
{
    const float* mean   = (const float*)d_in[0];
    const float* logvar = (const float*)d_in[1];
    const float* eps    = (const float*)d_in[2];
    float* out = (float*)d_out;

    unsigned* counter = (unsigned*)d_ws;
    float*    partial = (float*)((char*)d_ws + WS_PARTIAL);
    float4*   params  = (float4*)((char*)d_ws + WS_PARAMS);
    float2*   table   = (float2*)((char*)d_ws + WS_TABLE);
    float*    epsT    = (float*)((char*)d_ws + WS_EPST);

    ksetup<<<(B * D) / 256, 256, 0, stream>>>(mean, logvar, params, counter);
    if (ws_size >= (size_t)WS_NEED) {
        ktrans<<<NC * 256, 256, 0, stream>>>(eps, epsT);
        ktable<<<NC * D * 4, 256, 0, stream>>>(params, table);
        keval<<<NBLK, 256, 0, stream>>>(epsT, params, table, partial, counter, out);
    } else {
        kmain<<<NBLK, 256, 0, stream>>>(eps, params, partial, counter, out);
    }
}